// Round 3
// baseline (346.497 us; speedup 1.0000x reference)
//
#include <hip/hip_runtime.h>
#include <hip/hip_bf16.h>

#define V 50000
#define H 256
#define B 512

typedef __bf16 bf16x8 __attribute__((ext_vector_type(8)));
typedef float f32x4 __attribute__((ext_vector_type(4)));

__device__ __forceinline__ float tanh_fast(float x) {
    float a = __builtin_fabsf(x);
    float e = __expf(2.0f * a);                       // inf for large a -> r=1
    float r = fmaf(-2.0f, __builtin_amdgcn_rcpf(e + 1.0f), 1.0f);
    return __builtin_copysignf(r, x);
}

__device__ __forceinline__ float sigmoid_fast(float x) {
    return __builtin_amdgcn_rcpf(1.0f + __expf(-x));
}

// ---------------- Kernel A: gather + h0@w_hh.T + GRU cell ----------------
// 256 blocks x 512 threads, 2 batches per block, k-dim split in halves:
// thread (j, half) accumulates k in [half*128, half*128+128) for gate row j.
// Gives 2048 waves (2/SIMD) so the scattered one-hot gathers' HBM latency
// is hidden by other waves' dot-product work.
__global__ __launch_bounds__(512) void gru_h1_kernel(
    const int* __restrict__ ids, const float* __restrict__ h0,
    const float* __restrict__ w_ih, const float* __restrict__ w_hh,
    const float* __restrict__ b_ih, const float* __restrict__ b_hh,
    float* __restrict__ h1_out, __bf16* __restrict__ h1b)
{
    __shared__ float h0s[2][H];
    __shared__ float part[2][3][H];   // half==1 partial sums [batch][gate][j]
    const int t = threadIdx.x;
    const int j = t & (H - 1);
    const int half = t >> 8;          // 0/1
    const int b0 = blockIdx.x * 2;

    // Scattered one-hot gathers FIRST: ~900cyc HBM latency overlaps the dots.
    const int id0 = ids[b0], id1 = ids[b0 + 1];
    float gi[2][3];
    if (half == 0) {
#pragma unroll
        for (int g = 0; g < 3; g++) {
            gi[0][g] = w_ih[(size_t)(g * H + j) * V + id0];
            gi[1][g] = w_ih[(size_t)(g * H + j) * V + id1];
        }
    }
    h0s[half][j] = h0[(b0 + half) * H + j];
    __syncthreads();

    const int k0 = half * (H / 2);
    const float* __restrict__ wr = w_hh + (size_t)(0 * H + j) * H + k0;
    const float* __restrict__ wz = w_hh + (size_t)(1 * H + j) * H + k0;
    const float* __restrict__ wn = w_hh + (size_t)(2 * H + j) * H + k0;

    float ar[2] = {0.f, 0.f}, az[2] = {0.f, 0.f}, an[2] = {0.f, 0.f};
#pragma unroll 4
    for (int k = 0; k < H / 2; k += 4) {
        f32x4 vr = *(const f32x4*)(wr + k);
        f32x4 vz = *(const f32x4*)(wz + k);
        f32x4 vn = *(const f32x4*)(wn + k);
#pragma unroll
        for (int m = 0; m < 2; m++) {
            f32x4 h = *(const f32x4*)&h0s[m][k0 + k];  // LDS broadcast
#pragma unroll
            for (int u = 0; u < 4; u++) {
                ar[m] = fmaf(vr[u], h[u], ar[m]);
                az[m] = fmaf(vz[u], h[u], az[m]);
                an[m] = fmaf(vn[u], h[u], an[m]);
            }
        }
    }

    if (half == 1) {
#pragma unroll
        for (int m = 0; m < 2; m++) {
            part[m][0][j] = ar[m];
            part[m][1][j] = az[m];
            part[m][2][j] = an[m];
        }
    }
    __syncthreads();

    if (half == 0) {
        const float bir = b_ih[j], biz = b_ih[H + j], bin = b_ih[2 * H + j];
        const float bhr = b_hh[j], bhz = b_hh[H + j], bhn = b_hh[2 * H + j];
#pragma unroll
        for (int m = 0; m < 2; m++) {
            float sr = ar[m] + part[m][0][j];   // full h-dot, gate r
            float sz = az[m] + part[m][1][j];
            float sn = an[m] + part[m][2][j];
            float r = sigmoid_fast(gi[m][0] + bir + sr + bhr);
            float z = sigmoid_fast(gi[m][1] + biz + sz + bhz);
            float n = tanh_fast(gi[m][2] + bin + r * (sn + bhn));
            float h1 = (1.f - z) * n + z * h0s[m][j];
            h1_out[(b0 + m) * H + j] = h1;
            h1b[(b0 + m) * H + j] = (__bf16)h1;
        }
    }
}

// ---------------- Kernel B: logits = tanh(h1 @ w_out.T + b_out) ----------
// MFMA 16x16x32 bf16, SWAPPED operands: D = Wtile * h1^T, so each lane's 4
// acc regs are 4 CONSECUTIVE n-columns -> dwordx4 stores.
// ONE block per 64-row n-slab now covers ALL 512 m rows (8 waves x 64 m):
// w_out is fetched from HBM exactly once (51.2 MB, was 102.4 MB).
#define BN 64
#define BSTR 264  // 256 + 8 bf16 pad

__global__ __launch_bounds__(512) void logit_kernel(
    const __bf16* __restrict__ h1b, const float* __restrict__ w_out,
    const float* __restrict__ b_out, float* __restrict__ out)
{
    __shared__ __bf16 Bs[BN * BSTR];  // ~33 KB, [v][k] bf16 padded stride
    const int t = threadIdx.x;
    const int n0 = blockIdx.x * BN;

    // Stage w_out tile (64 rows x 256 k) fp32 -> bf16 into LDS.
    // Wave v0 loads rows v0*8..v0*8+7; each load = one full 1KB row.
    {
        const int c4 = t & 63;   // float4 column: k = c4*4
        const int v0 = t >> 6;   // wave id 0..7
        f32x4 g[8];
#pragma unroll
        for (int i = 0; i < 8; i++) {
            const int n = n0 + v0 * 8 + i;
            g[i] = (f32x4){0.f, 0.f, 0.f, 0.f};
            if (n < V) g[i] = *(const f32x4*)(w_out + (size_t)n * H + c4 * 4);
        }
#pragma unroll
        for (int i = 0; i < 8; i++) {
            const int v = v0 * 8 + i;
            struct alignas(8) BH4 { __bf16 h[4]; } p;
            p.h[0] = (__bf16)g[i][0];
            p.h[1] = (__bf16)g[i][1];
            p.h[2] = (__bf16)g[i][2];
            p.h[3] = (__bf16)g[i][3];
            *(BH4*)&Bs[v * BSTR + c4 * 4] = p;
        }
    }
    __syncthreads();

    const int lane = t & 63;
    const int wave = t >> 6;    // 0..7 -> m strip of 64
    const int q = lane >> 4;    // quad 0..3
    const int v16 = lane & 15;
    const int m_base = wave * 64;

    f32x4 acc[4][4];
#pragma unroll
    for (int i = 0; i < 4; i++)
#pragma unroll
        for (int jj = 0; jj < 4; jj++) acc[i][jj] = (f32x4){0.f, 0.f, 0.f, 0.f};

    const __bf16* a_base = h1b + (size_t)(m_base + v16) * H + q * 8;

#pragma unroll
    for (int ks = 0; ks < 8; ks++) {
        bf16x8 a[4];
#pragma unroll
        for (int i = 0; i < 4; i++)
            a[i] = *(const bf16x8*)(a_base + i * 16 * H + ks * 32);
#pragma unroll
        for (int jj = 0; jj < 4; jj++) {
            bf16x8 bfr = *(const bf16x8*)&Bs[(jj * 16 + v16) * BSTR + ks * 32 + q * 8];
#pragma unroll
            for (int i = 0; i < 4; i++)
                acc[i][jj] = __builtin_amdgcn_mfma_f32_16x16x32_bf16(
                    bfr, a[i], acc[i][jj], 0, 0, 0);  // SWAPPED: D[n][m]
        }
    }

    // Epilogue. Swapped C/D layout: lane holds m = m_base+i*16+v16 (col),
    // n = n0 + jj*16 + q*4 + reg (row). 4 regs = 4 consecutive n -> dwordx4.
#pragma unroll
    for (int jj = 0; jj < 4; jj++) {
        const int n = n0 + jj * 16 + q * 4;
        if (n < V) {  // V%4==0 so all 4 regs valid together
            f32x4 bo = *(const f32x4*)&b_out[n];
#pragma unroll
            for (int i = 0; i < 4; i++) {
                f32x4 r;
#pragma unroll
                for (int u = 0; u < 4; u++)
                    r[u] = tanh_fast(acc[i][jj][u] + bo[u]);
                *(f32x4*)&out[(size_t)(m_base + i * 16 + v16) * V + n] = r;
            }
        }
    }
}

extern "C" void kernel_launch(void* const* d_in, const int* in_sizes, int n_in,
                              void* d_out, int out_size, void* d_ws, size_t ws_size,
                              hipStream_t stream) {
    const int* ids = (const int*)d_in[0];
    const float* hidden = (const float*)d_in[1];
    const float* w_ih = (const float*)d_in[2];
    const float* w_hh = (const float*)d_in[3];
    const float* b_ih = (const float*)d_in[4];
    const float* b_hh = (const float*)d_in[5];
    const float* w_out = (const float*)d_in[6];
    const float* b_out = (const float*)d_in[7];

    float* out = (float*)d_out;
    float* h1_out = out + (size_t)B * V;
    __bf16* h1b = (__bf16*)d_ws;

    gru_h1_kernel<<<256, 512, 0, stream>>>(ids, hidden, w_ih, w_hh, b_ih, b_hh,
                                           h1_out, h1b);

    logit_kernel<<<(V + BN - 1) / BN, 512, 0, stream>>>(h1b, w_out, b_out, out);
}

// Round 4
// 334.229 us; speedup vs baseline: 1.0367x; 1.0367x over previous
//
#include <hip/hip_runtime.h>
#include <hip/hip_bf16.h>

#define V 50000
#define H 256
#define B 512

typedef __bf16 bf16x8 __attribute__((ext_vector_type(8)));
typedef float f32x4 __attribute__((ext_vector_type(4)));

__device__ __forceinline__ float tanh_fast(float x) {
    float a = __builtin_fabsf(x);
    float e = __expf(2.0f * a);                       // inf for large a -> r=1
    float r = fmaf(-2.0f, __builtin_amdgcn_rcpf(e + 1.0f), 1.0f);
    return __builtin_copysignf(r, x);
}

// ---------------- Kernel A: gather + h0@w_hh.T + GRU cell ----------------
// 256 blocks x 256 threads, 2 batches per block. Thread t owns gate index j=t.
// Proven config (333 us total): 1 wave/SIMD but gathers issued first so the
// ~900cyc scattered w_ih reads overlap the w_hh dot loop. Split-k variant
// (512 thr, 2 waves/SIMD) measured SLOWER overall (R3: +13us) - extra
// barriers + LDS combine cost more than the latency hiding bought.
__global__ __launch_bounds__(256) void gru_h1_kernel(
    const int* __restrict__ ids, const float* __restrict__ h0,
    const float* __restrict__ w_ih, const float* __restrict__ w_hh,
    const float* __restrict__ b_ih, const float* __restrict__ b_hh,
    float* __restrict__ h1_out, __bf16* __restrict__ h1b)
{
    __shared__ float h0s[2 * 256];
    const int t = threadIdx.x;
    const int b0 = blockIdx.x * 2;

#pragma unroll
    for (int i = 0; i < 2; i++)
        h0s[i * 256 + t] = h0[(b0 + i) * 256 + t];
    __syncthreads();

    const int j = t;

    // Issue the scattered one-hot gathers FIRST so their ~900cyc HBM latency
    // overlaps the w_hh dot-product loop.
    int id[2];
    float gir[2], giz[2], gin[2];
#pragma unroll
    for (int m = 0; m < 2; m++) {
        id[m] = ids[b0 + m];
        gir[m] = w_ih[(size_t)j * V + id[m]];
        giz[m] = w_ih[(size_t)(H + j) * V + id[m]];
        gin[m] = w_ih[(size_t)(2 * H + j) * V + id[m]];
    }

    float ar[2] = {0.f, 0.f}, az[2] = {0.f, 0.f}, an[2] = {0.f, 0.f};
    const float* __restrict__ wr_p = w_hh + (size_t)j * H;
    const float* __restrict__ wz_p = w_hh + (size_t)(H + j) * H;
    const float* __restrict__ wn_p = w_hh + (size_t)(2 * H + j) * H;

#pragma unroll 4
    for (int k = 0; k < H; k += 4) {
        f32x4 wr = *(const f32x4*)(wr_p + k);
        f32x4 wz = *(const f32x4*)(wz_p + k);
        f32x4 wn = *(const f32x4*)(wn_p + k);
#pragma unroll
        for (int m = 0; m < 2; m++) {
            f32x4 h = *(const f32x4*)&h0s[m * 256 + k];  // LDS broadcast
#pragma unroll
            for (int u = 0; u < 4; u++) {
                ar[m] = fmaf(wr[u], h[u], ar[m]);
                az[m] = fmaf(wz[u], h[u], az[m]);
                an[m] = fmaf(wn[u], h[u], an[m]);
            }
        }
    }

    const float bir = b_ih[j], biz = b_ih[H + j], bin = b_ih[2 * H + j];
    const float bhr = b_hh[j], bhz = b_hh[H + j], bhn = b_hh[2 * H + j];

#pragma unroll
    for (int m = 0; m < 2; m++) {
        float r = 1.f / (1.f + __expf(-(gir[m] + bir + ar[m] + bhr)));
        float z = 1.f / (1.f + __expf(-(giz[m] + biz + az[m] + bhz)));
        // n-gate is i_n + r*(h_n) with h_n = an + bhn
        float n = tanh_fast(gin[m] + bin + r * (an[m] + bhn));
        float h1 = (1.f - z) * n + z * h0s[m * 256 + j];
        h1_out[(b0 + m) * H + j] = h1;
        h1b[(b0 + m) * H + j] = (__bf16)h1;
    }
}

// ---------------- Kernel B: logits = tanh(h1 @ w_out.T + b_out) ----------
// MFMA 16x16x32 bf16, SWAPPED operands: D = Wtile * h1^T, so each lane's 4
// acc regs are 4 CONSECUTIVE n-columns -> dwordx4 stores.
// grid (782, 2) x 256 threads: the grid.y=2 "double fetch" of w_out is
// absorbed by the 256MB L3 (51.2MB working set), and the 2x block count
// gives a better dispatch tail than one 512-thread block per n-slab
// (R3 measured the "fetch-once" variant +13us slower).
#define BN 64
#define BSTR 264  // 256 + 8 bf16 pad

__global__ __launch_bounds__(256, 4) void logit_kernel(
    const __bf16* __restrict__ h1b, const float* __restrict__ w_out,
    const float* __restrict__ b_out, float* __restrict__ out)
{
    __shared__ __bf16 Bs[BN * BSTR];  // [v][k] bf16, padded stride
    const int t = threadIdx.x;
    const int n0 = blockIdx.x * BN;
    const int m_tile = blockIdx.y;

    // Stage w_out tile (64 rows x 256 k) fp32 -> bf16 into LDS.
    // Two batches of 8 loads so 8 x 1KB stay in flight per wave.
    {
        const int c4 = t & 63;  // float4 column: k = c4*4
        const int v0 = t >> 6;  // 0..3
#pragma unroll
        for (int half = 0; half < 2; half++) {
            f32x4 g[8];
#pragma unroll
            for (int i = 0; i < 8; i++) {
                int n = n0 + v0 + (half * 8 + i) * 4;
                g[i] = (f32x4){0.f, 0.f, 0.f, 0.f};
                if (n < V) g[i] = *(const f32x4*)(w_out + (size_t)n * H + c4 * 4);
            }
#pragma unroll
            for (int i = 0; i < 8; i++) {
                int v = v0 + (half * 8 + i) * 4;
                struct alignas(8) BH4 { __bf16 h[4]; } p;
                p.h[0] = (__bf16)g[i][0];
                p.h[1] = (__bf16)g[i][1];
                p.h[2] = (__bf16)g[i][2];
                p.h[3] = (__bf16)g[i][3];
                *(BH4*)&Bs[v * BSTR + c4 * 4] = p;
            }
        }
    }
    __syncthreads();

    const int lane = t & 63;
    const int wave = t >> 6;
    const int q = lane >> 4;    // quad 0..3
    const int v16 = lane & 15;
    const int m_base = m_tile * 256 + wave * 64;

    f32x4 acc[4][4];
#pragma unroll
    for (int i = 0; i < 4; i++)
#pragma unroll
        for (int jj = 0; jj < 4; jj++) acc[i][jj] = (f32x4){0.f, 0.f, 0.f, 0.f};

    const __bf16* a_base = h1b + (m_base + v16) * H + q * 8;

#pragma unroll
    for (int ks = 0; ks < 8; ks++) {
        bf16x8 a[4];
#pragma unroll
        for (int i = 0; i < 4; i++)
            a[i] = *(const bf16x8*)(a_base + i * 16 * H + ks * 32);
#pragma unroll
        for (int jj = 0; jj < 4; jj++) {
            bf16x8 bfr = *(const bf16x8*)&Bs[(jj * 16 + v16) * BSTR + ks * 32 + q * 8];
#pragma unroll
            for (int i = 0; i < 4; i++)
                acc[i][jj] = __builtin_amdgcn_mfma_f32_16x16x32_bf16(
                    bfr, a[i], acc[i][jj], 0, 0, 0);  // SWAPPED: D[n][m]
        }
    }

    // Epilogue. Swapped C/D layout: lane holds m = m_base+i*16+v16 (col),
    // n = n0 + jj*16 + q*4 + reg (row). 4 regs = 4 consecutive n -> dwordx4.
#pragma unroll
    for (int jj = 0; jj < 4; jj++) {
        const int n = n0 + jj * 16 + q * 4;
        if (n < V) {  // V%4==0 so all 4 lanes' elems valid together
            f32x4 bo = *(const f32x4*)&b_out[n];
#pragma unroll
            for (int i = 0; i < 4; i++) {
                f32x4 r;
#pragma unroll
                for (int u = 0; u < 4; u++)
                    r[u] = tanh_fast(acc[i][jj][u] + bo[u]);
                *(f32x4*)&out[(size_t)(m_base + i * 16 + v16) * V + n] = r;
            }
        }
    }
}

extern "C" void kernel_launch(void* const* d_in, const int* in_sizes, int n_in,
                              void* d_out, int out_size, void* d_ws, size_t ws_size,
                              hipStream_t stream) {
    const int* ids = (const int*)d_in[0];
    const float* hidden = (const float*)d_in[1];
    const float* w_ih = (const float*)d_in[2];
    const float* w_hh = (const float*)d_in[3];
    const float* b_ih = (const float*)d_in[4];
    const float* b_hh = (const float*)d_in[5];
    const float* w_out = (const float*)d_in[6];
    const float* b_out = (const float*)d_in[7];

    float* out = (float*)d_out;
    float* h1_out = out + (size_t)B * V;
    __bf16* h1b = (__bf16*)d_ws;

    gru_h1_kernel<<<256, 256, 0, stream>>>(ids, hidden, w_ih, w_hh, b_ih, b_hh,
                                           h1_out, h1b);

    dim3 grid((V + BN - 1) / BN, 2);  // x = n-slab, y = m-tile
    logit_kernel<<<grid, 256, 0, stream>>>(h1b, w_out, b_out, out);
}